// Round 9
// baseline (966.804 us; speedup 1.0000x reference)
//
#include <hip/hip_runtime.h>

// ---------------------------------------------------------------------------
// NeuralCA fused step, multi-launch, 4 waves/SIMD:
//   512-thread blocks (8 waves), 2-row blocks, 448 blocks, 2 blocks/CU
//   (63.7 KB LDS), __launch_bounds__(512,4) -> VGPR cap 128/wave.
//   waves 0-3 (G1, quarter wq): h1 chans 32wq..32wq+31 of tiles {2j,2j+1}
//   waves 4-7 (G23, quarter g): G2 chans 32g..+31 of tiles {2(j-1),2(j-1)+1};
//        waves g<2 also: G3 full-K + epilogue of tile 2(j-2)+g
//   h1/h2 via double-buffered LDS mailboxes, 1 lgkm-only barrier per iter.
//   XCD-bijective swizzle (R15, -25us): 448 = 8 XCDs x 56 contiguous bands.
//
//   R16 (on R15 champion, 960.8us): remove residual mechanical waste.
//   (i) G1 exact K=144: was padded to 160 via off>8 clamp (4/20 MFMA + 2/10
//       reads multiply ZERO weight rows). Now 4x K32 MFMA + one 16x16x16
//       bf16 tail MFMA (K 128..143, off=8). -10 cyc MFMA, -2 reads per
//       G1 wave-iter. __has_builtin-guarded; fallback = old clamp path.
//   (ii) G3 dependent-chain split: 4 serial MFMAs -> 2 interleaved 2-chains
//       (residual seeds chain A) + final add. ~-20 cyc on the heaviest
//       (barrier-setting) wave class.
//   Evidence: R11 -19 (LDS write conflicts), R15 -25 (XCD swizzle); all
//   schedule restructures (R8,R12,R13,R14) regressed -> only waste-removal
//   wins on this structure. LDS patterns audited: reads/writes at wave64
//   bank floor, nothing else mechanical left.
// ---------------------------------------------------------------------------

typedef __attribute__((ext_vector_type(8))) short short8;
typedef __attribute__((ext_vector_type(4))) short short4v;
typedef __attribute__((ext_vector_type(4))) float float4v;
typedef __attribute__((ext_vector_type(2))) unsigned int uint2v;

#define MFMA16(a, b, c) __builtin_amdgcn_mfma_f32_16x16x32_bf16((a), (b), (c), 0, 0, 0)

#if __has_builtin(__builtin_amdgcn_mfma_f32_16x16x16bf16_1k)
#define TAIL16 1
#define MFMA16T(a, b, c) __builtin_amdgcn_mfma_f32_16x16x16bf16_1k((a), (b), (c), 0, 0, 0)
#else
#define TAIL16 0
#endif

__device__ __forceinline__ short f2bf(float f) {
  unsigned u = __builtin_bit_cast(unsigned, f);
  return (short)((u + 0x8000u) >> 16);     // round-half-up
}

__device__ __forceinline__ unsigned pk2bf(float a, float b) {
#if __has_builtin(__builtin_amdgcn_cvt_pk_bf16_f32)
  typedef __attribute__((ext_vector_type(2))) __bf16 bf2;
  bf2 r = __builtin_amdgcn_cvt_pk_bf16_f32(a, b);
  return __builtin_bit_cast(unsigned, r);
#else
  unsigned ua = __builtin_bit_cast(unsigned, a), ub = __builtin_bit_cast(unsigned, b);
  return ((ua + 0x8000u) >> 16) | (((ub + 0x8000u) >> 16) << 16);
#endif
}

__device__ __forceinline__ void async16(const void* g, void* l) {
  __builtin_amdgcn_global_load_lds((const __attribute__((address_space(1))) void*)g,
                                   (__attribute__((address_space(3))) void*)l,
                                   16, 0, 0);
}

// LDS-only barrier (no vmcnt drain - global stores fly free)
__device__ __forceinline__ void sync_lds() {
  asm volatile("s_waitcnt lgkmcnt(0)\n\ts_barrier" ::: "memory");
}

// ---- workspace layout (bytes) ----
#define WS_WE    0          // W_eff^T [128][168] bf16 (K pad 144->168, zeros)
#define WS_W2    43008      // W2      [128][136] bf16 (K identity, pad 136)
#define WS_W3    77824      // W3      [ 16][136] bf16 (identity, pad 2560)
#define WS_B1    82944      // b1 f32 [128] (identity)
#define WS_B2    83456      // b2 f32 [128] (identity)
#define WS_X32A  83968
#define WS_X32B  12929024
#define WS_X16A  25774080
#define WS_X16B  32196608

// ---------------------------------------------------------------------------
__global__ void prep_x(const float* __restrict__ x, float* __restrict__ x32,
                       short* __restrict__ x16) {
  int i = blockIdx.x * 256 + threadIdx.x;          // exactly 3211264 threads
  int w = i % 224;
  int h = (i / 224) % 224;
  int c = (i / 50176) & 15;
  int bb = i / 802816;
  float v = x[i];
  int o = ((bb * 224 + h) * 224 + w) * 16 + c;     // NHWC
  x32[o] = v;
  x16[o] = f2bf(v);
}

// identity layouts (operand-swapped mailboxes store chpos == channel)
__global__ void prep_w(const float* __restrict__ wp, const float* __restrict__ w1,
                       const float* __restrict__ b1, const float* __restrict__ w2,
                       const float* __restrict__ b2, const float* __restrict__ w3,
                       short* __restrict__ wE, short* __restrict__ w2t,
                       short* __restrict__ w3t, float* __restrict__ b1p,
                       float* __restrict__ b2p) {
  int i = blockIdx.x * 256 + threadIdx.x;          // exactly 41728 threads
  if (i < 21504) {                                  // W_eff [o=128][k=168]
    int o = i / 168, k = i % 168;
    float v = 0.f;
    if (k < 144) {
      int off = k >> 4, c = k & 15;                 // k = offset*16 + c
      for (int c3 = 0; c3 < 48; ++c3)
        v += w1[o * 48 + c3] * wp[c3 * 144 + c * 9 + off];
    }
    wE[i] = f2bf(v);
  } else if (i < 38912) {                           // W2 [n=128][kk=136]
    int j = i - 21504;
    int n = j / 136, kk = j % 136;
    w2t[j] = (kk < 128) ? f2bf(w2[n * 128 + kk]) : (short)0;
  } else if (i < 41472) {                           // W3 [16][136], pad 2560
    int j = i - 38912;
    float v = 0.f;
    if (j < 2176) {
      int n = j / 136, kk = j % 136;
      if (kk < 128) v = w3[n * 128 + kk];
    }
    w3t[j] = f2bf(v);
  } else if (i < 41600) {
    int p = i - 41472;
    b1p[p] = b1[p];
  } else {
    int p = i - 41600;
    b2p[p] = b2[p];
  }
}

// ---------------------------------------------------------------------------
// One CA step. Block = 2 image rows, 512 threads = 8 waves. 28 tiles of
// 16 px; pipeline over 16 iterations:
//   G1 wave wq:  iter j<14:     chan-quarter of h1, tiles {2j,2j+1} -> sBUF j&1
//   G23 wave g:  iter 1<=j<=14: chan-quarter of h2, tiles {2(j-1),..} -> sH2 j&1
//   G23 g<2:     iter j>=2:     G3 full-K + epilogue, tile 2(j-2)+g
template <bool LAST>
__global__ __launch_bounds__(512, 4) void ca_step(
    const short* __restrict__ wEg, const short* __restrict__ w2g,
    const short* __restrict__ w3g, const float* __restrict__ b1p,
    const float* __restrict__ b2p, const float* __restrict__ xs32,
    const short* __restrict__ xs16, float* __restrict__ xd32,
    short* __restrict__ xd16, float* __restrict__ dout) {
  __shared__ short sXH[4 * 3616];       // 28928 B  halo: 4 rows x 226 x 16ch
  __shared__ short sBUF[2 * 2 * 2176];  // 17408 B  h1 mailbox dbuf x 2 tiles
  __shared__ short sH2[2 * 2 * 2176];   // 17408 B  h2 dbuf x 2 tiles
  // total 63744 B -> 2 blocks/CU, 16 waves/CU = 4 waves/SIMD

  const int tid = threadIdx.x;
  const int lane = tid & 63;
  const int wv = tid >> 6;              // 0..7
  const int c16 = lane & 15;
  const int q = lane >> 4;
  const int q8 = q * 8;
  const int qh = q >> 1;
  const int c0 = (q & 1) * 8;

  // XCD-bijective swizzle: 448 = 8 XCDs x 56. blockIdx&7 = XCD (round-robin
  // dispatch); x56 -> each XCD owns a contiguous half-batch band across all
  // 40 launches, so step-s state writes are step-s+1 L2-local reads.
  const int blk = (blockIdx.x & 7) * 56 + (blockIdx.x >> 3);
  const int b = blk / 112;              // 4 batches x 112 rowgroups
  const int h0 = (blk % 112) * 2;

  // ---- stage halo: 4 rows x 7 chunks (1KB each); OOB rows -> zeros ----
  const short8 z8 = {0, 0, 0, 0, 0, 0, 0, 0};
  for (int t = wv; t < 28; t += 8) {
    int hr = t / 7, ck = t % 7;
    int hh = h0 - 1 + hr;
    char* l = (char*)sXH + hr * 7232 + 32 + ck * 1024;  // col 0 = image col -1
    if (hh >= 0 && hh < 224) {
      const char* g = (const char*)xs16 + ((size_t)(b * 224 + hh) * 224) * 32 + ck * 1024;
      async16(g + lane * 16, l);
    } else {
      *(short8*)(l + lane * 16) = z8;
    }
  }
  if (tid < 16) {   // zero edge columns (image col -1 and 224) for all 4 rows
    int hr = tid >> 2, wch = tid & 3;
    int colb = (wch < 2) ? 0 : 225;
    *(short8*)((char*)sXH + hr * 7232 + colb * 32 + (wch & 1) * 16) = z8;
  }

  if (wv < 4) {
    // ====== G1 role, chan-quarter wq: conv3x3+MLP1 fused (A=W, B=x) ======
    const int wq = wv;
    const int obase = 32 * wq;          // channel rows 32wq..32wq+31
#if TAIL16
    short8 wf[4][2];                    // 32 VGPR; K 0..127
    short4v wfT[2];                     // 4 VGPR;  K 128..143 (off=8)
#pragma unroll
    for (int kc = 0; kc < 4; ++kc)
#pragma unroll
      for (int n = 0; n < 2; ++n)
        wf[kc][n] = *(const short8*)(wEg + (obase + 16 * n + c16) * 168 + kc * 32 + q8);
#pragma unroll
    for (int n = 0; n < 2; ++n)
      wfT[n] = *(const short4v*)(wEg + (obase + 16 * n + c16) * 168 + 128 + 4 * q);
#else
    short8 wf[5][2];                    // 40 VGPR (padded K=160 path)
#pragma unroll
    for (int kc = 0; kc < 5; ++kc)
#pragma unroll
      for (int n = 0; n < 2; ++n)
        wf[kc][n] = *(const short8*)(wEg + (obase + 16 * n + c16) * 168 + kc * 32 + q8);
#endif
    float4v bH[2];                      // bias for chans obase+16n+4q..+3
#pragma unroll
    for (int n = 0; n < 2; ++n)
      bH[n] = *(const float4v*)(b1p + obase + 16 * n + 4 * q);

    __syncthreads();                    // halo ready (drains vmcnt)

    for (int j = 0; j < 16; ++j) {
      if (j < 14) {
        const int t0 = 2 * j, t1 = t0 + 1;
        const int hb0 = ((t0 / 14) * 226 + (t0 % 14) * 16) * 16;
        const int hb1 = ((t1 / 14) * 226 + (t1 % 14) * 16) * 16;
        float4v acc[2][2];
#pragma unroll
        for (int tt = 0; tt < 2; ++tt)
#pragma unroll
          for (int n = 0; n < 2; ++n) acc[tt][n] = (float4v){0.f, 0.f, 0.f, 0.f};
        __builtin_amdgcn_s_setprio(1);
#pragma unroll
        for (int kc = 0; kc < 4; ++kc) {
          const int off = kc * 2 + qh;  // 0..7, exact
          const int dy = (off * 11) >> 5;     // off/3
          const int dxx = off - dy * 3;
          const int ao = (dy * 226 + dxx + c16) * 16 + c0;
          short8 a0 = *(const short8*)(sXH + hb0 + ao);   // B-frag
          short8 a1 = *(const short8*)(sXH + hb1 + ao);
#pragma unroll
          for (int n = 0; n < 2; ++n) {
            acc[0][n] = MFMA16(wf[kc][n], a0, acc[0][n]);
            acc[1][n] = MFMA16(wf[kc][n], a1, acc[1][n]);
          }
        }
#if TAIL16
        {                               // K tail 128..143: off=8 (dy=2,dxx=2)
          const int at = (2 * 226 + 2 + c16) * 16 + 4 * q;
          short4v t0v = *(const short4v*)(sXH + hb0 + at);
          short4v t1v = *(const short4v*)(sXH + hb1 + at);
#pragma unroll
          for (int n = 0; n < 2; ++n) {
            acc[0][n] = MFMA16T(wfT[n], t0v, acc[0][n]);
            acc[1][n] = MFMA16T(wfT[n], t1v, acc[1][n]);
          }
        }
#else
        {                               // padded path: off clamped to 8
          const int ao = (2 * 226 + 2 + c16) * 16 + c0;
          short8 a0 = *(const short8*)(sXH + hb0 + ao);
          short8 a1 = *(const short8*)(sXH + hb1 + ao);
#pragma unroll
          for (int n = 0; n < 2; ++n) {
            acc[0][n] = MFMA16(wf[4][n], a0, acc[0][n]);
            acc[1][n] = MFMA16(wf[4][n], a1, acc[1][n]);
          }
        }
#endif
        __builtin_amdgcn_s_setprio(0);
        // D[ch][px]: lane=px(c16), regs=4 consecutive ch -> b64 writes
#pragma unroll
        for (int tt = 0; tt < 2; ++tt) {
          short* dst = sBUF + ((j & 1) * 2 + tt) * 2176 + c16 * 136;
#pragma unroll
          for (int n = 0; n < 2; ++n) {
            unsigned d0 = pk2bf(fmaxf(acc[tt][n][0] + bH[n][0], 0.f),
                                fmaxf(acc[tt][n][1] + bH[n][1], 0.f));
            unsigned d1 = pk2bf(fmaxf(acc[tt][n][2] + bH[n][2], 0.f),
                                fmaxf(acc[tt][n][3] + bH[n][3], 0.f));
            *(uint2v*)(dst + obase + 16 * n + 4 * q) = (uint2v){d0, d1};
          }
        }
      }
      sync_lds();
    }
  } else {
    // ====== G23 role, chan-quarter g: MLP2 (A=W2, B=h1) + (g<2) MLP3 =====
    const int g = wv - 4;
    const int obase = 32 * g;
    short8 w2f[4][2];                   // 32 VGPR; A-frag row obase+16n+c16
    short8 w3f[4];                      // 16 VGPR
#pragma unroll
    for (int kc = 0; kc < 4; ++kc)
#pragma unroll
      for (int n = 0; n < 2; ++n)
        w2f[kc][n] = *(const short8*)(w2g + (obase + 16 * n + c16) * 136 + kc * 32 + q8);
#pragma unroll
    for (int kc = 0; kc < 4; ++kc)
      w3f[kc] = *(const short8*)(w3g + c16 * 136 + kc * 32 + q8);
    float4v bG[2];
#pragma unroll
    for (int n = 0; n < 2; ++n)
      bG[n] = *(const float4v*)(b2p + obase + 16 * n + 4 * q);

    __syncthreads();                    // halo ready

    for (int j = 0; j < 16; ++j) {
      float4v acc3;
      int cb3 = 0, hglob3 = 0;
      const bool doG3 = (g < 2) && (j >= 2);
      if (doG3) {                       // residual (b128) -> MFMA C-in
        const int t3 = 2 * (j - 2) + g;
        cb3 = (t3 % 14) * 16; hglob3 = h0 + t3 / 14;
        const size_t pix = (size_t)(b * 224 + hglob3) * 224 + cb3 + c16;
        acc3 = *(const float4v*)(xs32 + pix * 16 + q * 4);
      }
      if (j >= 1 && j <= 14) {          // G2 quarter on tiles 2(j-1), 2(j-1)+1
        const short* srcA = sBUF + (((j - 1) & 1) * 2 + 0) * 2176;
        const short* srcB = sBUF + (((j - 1) & 1) * 2 + 1) * 2176;
        float4v acc2[2][2];
#pragma unroll
        for (int tt = 0; tt < 2; ++tt)
#pragma unroll
          for (int n = 0; n < 2; ++n) acc2[tt][n] = (float4v){0.f, 0.f, 0.f, 0.f};
        __builtin_amdgcn_s_setprio(1);
#pragma unroll
        for (int kc = 0; kc < 4; ++kc) {
          short8 aA = *(const short8*)(srcA + c16 * 136 + kc * 32 + q8);  // B-frag
          short8 aB = *(const short8*)(srcB + c16 * 136 + kc * 32 + q8);
#pragma unroll
          for (int n = 0; n < 2; ++n) {
            acc2[0][n] = MFMA16(w2f[kc][n], aA, acc2[0][n]);
            acc2[1][n] = MFMA16(w2f[kc][n], aB, acc2[1][n]);
          }
        }
        __builtin_amdgcn_s_setprio(0);
        // D[ch2][px] -> b64 writes, conflict-free
#pragma unroll
        for (int tt = 0; tt < 2; ++tt) {
          short* dsth2 = sH2 + ((j & 1) * 2 + tt) * 2176 + c16 * 136;
#pragma unroll
          for (int n = 0; n < 2; ++n) {
            unsigned d0 = pk2bf(fmaxf(acc2[tt][n][0] + bG[n][0], 0.f),
                                fmaxf(acc2[tt][n][1] + bG[n][1], 0.f));
            unsigned d1 = pk2bf(fmaxf(acc2[tt][n][2] + bG[n][2], 0.f),
                                fmaxf(acc2[tt][n][3] + bG[n][3], 0.f));
            *(uint2v*)(dsth2 + obase + 16 * n + 4 * q) = (uint2v){d0, d1};
          }
        }
      }
      if (doG3) {                       // G3 full-K + epilogue, tile 2(j-2)+g
        // A=w3f, B=h2frag: D[ch][px]; two interleaved 2-chains halve the
        // dependent-MFMA latency on this (barrier-setting) wave class.
        const short* srch2 = sH2 + (((j - 1) & 1) * 2 + g) * 2176;
        float4v accB = (float4v){0.f, 0.f, 0.f, 0.f};
        __builtin_amdgcn_s_setprio(1);
        {
          short8 a0 = *(const short8*)(srch2 + c16 * 136 + 0 * 32 + q8);
          short8 a1 = *(const short8*)(srch2 + c16 * 136 + 1 * 32 + q8);
          short8 a2 = *(const short8*)(srch2 + c16 * 136 + 2 * 32 + q8);
          short8 a3 = *(const short8*)(srch2 + c16 * 136 + 3 * 32 + q8);
          acc3 = MFMA16(w3f[0], a0, acc3);
          accB = MFMA16(w3f[1], a1, accB);
          acc3 = MFMA16(w3f[2], a2, acc3);
          accB = MFMA16(w3f[3], a3, accB);
        }
        __builtin_amdgcn_s_setprio(0);
        float4v vv;
#pragma unroll
        for (int r = 0; r < 4; ++r)
          vv[r] = fminf(fmaxf(acc3[r] + accB[r], 0.f), 1.f);
        if (LAST) {
#pragma unroll
          for (int r = 0; r < 4; ++r)
            dout[((size_t)(b * 16 + q * 4 + r) * 224 + hglob3) * 224 + cb3 + c16] = vv[r];
        } else {
          const size_t pix = (size_t)(b * 224 + hglob3) * 224 + cb3 + c16;
          *(float4v*)(xd32 + pix * 16 + q * 4) = vv;          // 1x b128
          *(uint2v*)(xd16 + pix * 16 + q * 4) =               // 1x b64
              (uint2v){pk2bf(vv[0], vv[1]), pk2bf(vv[2], vv[3])};
        }
      }
      sync_lds();
    }
  }
}

// ---------------------------------------------------------------------------
extern "C" void kernel_launch(void* const* d_in, const int* in_sizes, int n_in,
                              void* d_out, int out_size, void* d_ws, size_t ws_size,
                              hipStream_t stream) {
  const float* x  = (const float*)d_in[0];
  const float* wp = (const float*)d_in[1];
  const float* w1 = (const float*)d_in[2];
  const float* b1 = (const float*)d_in[3];
  const float* w2 = (const float*)d_in[4];
  const float* b2 = (const float*)d_in[5];
  const float* w3 = (const float*)d_in[6];

  char* ws = (char*)d_ws;
  short* wEg = (short*)(ws + WS_WE);
  short* w2g = (short*)(ws + WS_W2);
  short* w3g = (short*)(ws + WS_W3);
  float* b1p = (float*)(ws + WS_B1);
  float* b2p = (float*)(ws + WS_B2);
  float* X32[2] = {(float*)(ws + WS_X32A), (float*)(ws + WS_X32B)};
  short* X16[2] = {(short*)(ws + WS_X16A), (short*)(ws + WS_X16B)};

  prep_x<<<12544, 256, 0, stream>>>(x, X32[0], X16[0]);
  prep_w<<<163, 256, 0, stream>>>(wp, w1, b1, w2, b2, w3, wEg, w2g, w3g, b1p, b2p);

  for (int s = 0; s < 39; ++s) {
    int sb = s & 1;
    ca_step<false><<<448, 512, 0, stream>>>(wEg, w2g, w3g, b1p, b2p,
                                            X32[sb], X16[sb],
                                            X32[1 - sb], X16[1 - sb], nullptr);
  }
  ca_step<true><<<448, 512, 0, stream>>>(wEg, w2g, w3g, b1p, b2p,
                                         X32[1], X16[1],
                                         X32[0], X16[0], (float*)d_out);
}

// Round 10
// 960.474 us; speedup vs baseline: 1.0066x; 1.0066x over previous
//
#include <hip/hip_runtime.h>

// ---------------------------------------------------------------------------
// NeuralCA fused step, multi-launch, 4 waves/SIMD:
//   512-thread blocks (8 waves), 2-row blocks, 448 blocks, 2 blocks/CU
//   (63.7 KB LDS), __launch_bounds__(512,4) -> VGPR cap 128/wave.
//   waves 0-3 (G1, quarter wq): h1 chans 32wq..32wq+31 of tiles {2j,2j+1}
//   waves 4-7 (G23, quarter g): G2 chans 32g..+31 of tiles {2(j-1),2(j-1)+1};
//        waves g<2 also: G3 full-K + epilogue of tile 2(j-2)+g
//   h1/h2 via double-buffered LDS mailboxes, 1 lgkm-only barrier per iter.
//   XCD-bijective swizzle (R15, -25us): 448 = 8 XCDs x 56 contiguous bands.
//
//   R17 = R15 champion MINUS s_setprio wrappers (R16 exact-K/chain-split
//   REVERTED, +6us). setprio entered in the R9 bundle (net 0) and was never
//   isolated. Evidence (m190 + this kernel's structure): in barrier-lockstep
//   schedules all waves reach their MFMA clusters together -> elevating all
//   waves elevates none; the toggles are pure SALU/scheduler churn at the
//   hottest points. Removal = the waste-removal pattern that produced both
//   wins (R11 -19us LDS write conflicts, R15 -25us XCD swizzle).
//   Ledger: R8 +19, R9 0, R12 +282, R13 +33, R14 +23, R16 +6 -> all
//   restructures regress; fusion/persistent/occupancy ruled out by
//   arithmetic (redundant halo > launch overhead; VGPR 95-100 > 84 for
//   3 blk/CU; prior-session demotion at persistent loop).
// ---------------------------------------------------------------------------

typedef __attribute__((ext_vector_type(8))) short short8;
typedef __attribute__((ext_vector_type(4))) float float4v;
typedef __attribute__((ext_vector_type(2))) unsigned int uint2v;

#define MFMA16(a, b, c) __builtin_amdgcn_mfma_f32_16x16x32_bf16((a), (b), (c), 0, 0, 0)

__device__ __forceinline__ short f2bf(float f) {
  unsigned u = __builtin_bit_cast(unsigned, f);
  return (short)((u + 0x8000u) >> 16);     // round-half-up
}

__device__ __forceinline__ unsigned pk2bf(float a, float b) {
#if __has_builtin(__builtin_amdgcn_cvt_pk_bf16_f32)
  typedef __attribute__((ext_vector_type(2))) __bf16 bf2;
  bf2 r = __builtin_amdgcn_cvt_pk_bf16_f32(a, b);
  return __builtin_bit_cast(unsigned, r);
#else
  unsigned ua = __builtin_bit_cast(unsigned, a), ub = __builtin_bit_cast(unsigned, b);
  return ((ua + 0x8000u) >> 16) | (((ub + 0x8000u) >> 16) << 16);
#endif
}

__device__ __forceinline__ void async16(const void* g, void* l) {
  __builtin_amdgcn_global_load_lds((const __attribute__((address_space(1))) void*)g,
                                   (__attribute__((address_space(3))) void*)l,
                                   16, 0, 0);
}

// LDS-only barrier (no vmcnt drain - global stores fly free)
__device__ __forceinline__ void sync_lds() {
  asm volatile("s_waitcnt lgkmcnt(0)\n\ts_barrier" ::: "memory");
}

// ---- workspace layout (bytes) ----
#define WS_WE    0          // W_eff^T [128][168] bf16 (K pad 144->168, zeros)
#define WS_W2    43008      // W2      [128][136] bf16 (K identity, pad 136)
#define WS_W3    77824      // W3      [ 16][136] bf16 (identity, pad 2560)
#define WS_B1    82944      // b1 f32 [128] (identity)
#define WS_B2    83456      // b2 f32 [128] (identity)
#define WS_X32A  83968
#define WS_X32B  12929024
#define WS_X16A  25774080
#define WS_X16B  32196608

// ---------------------------------------------------------------------------
__global__ void prep_x(const float* __restrict__ x, float* __restrict__ x32,
                       short* __restrict__ x16) {
  int i = blockIdx.x * 256 + threadIdx.x;          // exactly 3211264 threads
  int w = i % 224;
  int h = (i / 224) % 224;
  int c = (i / 50176) & 15;
  int bb = i / 802816;
  float v = x[i];
  int o = ((bb * 224 + h) * 224 + w) * 16 + c;     // NHWC
  x32[o] = v;
  x16[o] = f2bf(v);
}

// identity layouts (operand-swapped mailboxes store chpos == channel)
__global__ void prep_w(const float* __restrict__ wp, const float* __restrict__ w1,
                       const float* __restrict__ b1, const float* __restrict__ w2,
                       const float* __restrict__ b2, const float* __restrict__ w3,
                       short* __restrict__ wE, short* __restrict__ w2t,
                       short* __restrict__ w3t, float* __restrict__ b1p,
                       float* __restrict__ b2p) {
  int i = blockIdx.x * 256 + threadIdx.x;          // exactly 41728 threads
  if (i < 21504) {                                  // W_eff [o=128][k=168]
    int o = i / 168, k = i % 168;
    float v = 0.f;
    if (k < 144) {
      int off = k >> 4, c = k & 15;                 // k = offset*16 + c
      for (int c3 = 0; c3 < 48; ++c3)
        v += w1[o * 48 + c3] * wp[c3 * 144 + c * 9 + off];
    }
    wE[i] = f2bf(v);
  } else if (i < 38912) {                           // W2 [n=128][kk=136]
    int j = i - 21504;
    int n = j / 136, kk = j % 136;
    w2t[j] = (kk < 128) ? f2bf(w2[n * 128 + kk]) : (short)0;
  } else if (i < 41472) {                           // W3 [16][136], pad 2560
    int j = i - 38912;
    float v = 0.f;
    if (j < 2176) {
      int n = j / 136, kk = j % 136;
      if (kk < 128) v = w3[n * 128 + kk];
    }
    w3t[j] = f2bf(v);
  } else if (i < 41600) {
    int p = i - 41472;
    b1p[p] = b1[p];
  } else {
    int p = i - 41600;
    b2p[p] = b2[p];
  }
}

// ---------------------------------------------------------------------------
// One CA step. Block = 2 image rows, 512 threads = 8 waves. 28 tiles of
// 16 px; pipeline over 16 iterations:
//   G1 wave wq:  iter j<14:     chan-quarter of h1, tiles {2j,2j+1} -> sBUF j&1
//   G23 wave g:  iter 1<=j<=14: chan-quarter of h2, tiles {2(j-1),..} -> sH2 j&1
//   G23 g<2:     iter j>=2:     G3 full-K + epilogue, tile 2(j-2)+g
template <bool LAST>
__global__ __launch_bounds__(512, 4) void ca_step(
    const short* __restrict__ wEg, const short* __restrict__ w2g,
    const short* __restrict__ w3g, const float* __restrict__ b1p,
    const float* __restrict__ b2p, const float* __restrict__ xs32,
    const short* __restrict__ xs16, float* __restrict__ xd32,
    short* __restrict__ xd16, float* __restrict__ dout) {
  __shared__ short sXH[4 * 3616];       // 28928 B  halo: 4 rows x 226 x 16ch
  __shared__ short sBUF[2 * 2 * 2176];  // 17408 B  h1 mailbox dbuf x 2 tiles
  __shared__ short sH2[2 * 2 * 2176];   // 17408 B  h2 dbuf x 2 tiles
  // total 63744 B -> 2 blocks/CU, 16 waves/CU = 4 waves/SIMD

  const int tid = threadIdx.x;
  const int lane = tid & 63;
  const int wv = tid >> 6;              // 0..7
  const int c16 = lane & 15;
  const int q = lane >> 4;
  const int q8 = q * 8;
  const int qh = q >> 1;
  const int c0 = (q & 1) * 8;

  // XCD-bijective swizzle: 448 = 8 XCDs x 56. blockIdx&7 = XCD (round-robin
  // dispatch); x56 -> each XCD owns a contiguous half-batch band across all
  // 40 launches, so step-s state writes are step-s+1 L2-local reads.
  const int blk = (blockIdx.x & 7) * 56 + (blockIdx.x >> 3);
  const int b = blk / 112;              // 4 batches x 112 rowgroups
  const int h0 = (blk % 112) * 2;

  // ---- stage halo: 4 rows x 7 chunks (1KB each); OOB rows -> zeros ----
  const short8 z8 = {0, 0, 0, 0, 0, 0, 0, 0};
  for (int t = wv; t < 28; t += 8) {
    int hr = t / 7, ck = t % 7;
    int hh = h0 - 1 + hr;
    char* l = (char*)sXH + hr * 7232 + 32 + ck * 1024;  // col 0 = image col -1
    if (hh >= 0 && hh < 224) {
      const char* g = (const char*)xs16 + ((size_t)(b * 224 + hh) * 224) * 32 + ck * 1024;
      async16(g + lane * 16, l);
    } else {
      *(short8*)(l + lane * 16) = z8;
    }
  }
  if (tid < 16) {   // zero edge columns (image col -1 and 224) for all 4 rows
    int hr = tid >> 2, wch = tid & 3;
    int colb = (wch < 2) ? 0 : 225;
    *(short8*)((char*)sXH + hr * 7232 + colb * 32 + (wch & 1) * 16) = z8;
  }

  if (wv < 4) {
    // ====== G1 role, chan-quarter wq: conv3x3+MLP1 fused (A=W, B=x) ======
    const int wq = wv;
    const int obase = 32 * wq;          // channel rows 32wq..32wq+31
    short8 wf[5][2];                    // 40 VGPR; A-frag: row obase+16n+c16
#pragma unroll
    for (int kc = 0; kc < 5; ++kc)
#pragma unroll
      for (int n = 0; n < 2; ++n)
        wf[kc][n] = *(const short8*)(wEg + (obase + 16 * n + c16) * 168 + kc * 32 + q8);
    float4v bH[2];                      // bias for chans obase+16n+4q..+3
#pragma unroll
    for (int n = 0; n < 2; ++n)
      bH[n] = *(const float4v*)(b1p + obase + 16 * n + 4 * q);

    __syncthreads();                    // halo ready (drains vmcnt)

    for (int j = 0; j < 16; ++j) {
      if (j < 14) {
        const int t0 = 2 * j, t1 = t0 + 1;
        const int hb0 = ((t0 / 14) * 226 + (t0 % 14) * 16) * 16;
        const int hb1 = ((t1 / 14) * 226 + (t1 % 14) * 16) * 16;
        float4v acc[2][2];
#pragma unroll
        for (int tt = 0; tt < 2; ++tt)
#pragma unroll
          for (int n = 0; n < 2; ++n) acc[tt][n] = (float4v){0.f, 0.f, 0.f, 0.f};
#pragma unroll
        for (int kc = 0; kc < 5; ++kc) {
          int off = kc * 2 + qh;
          if (off > 8) off = 8;         // K 144..159 hit zero rows of W_eff
          int dy = (off * 11) >> 5;     // off/3
          int dxx = off - dy * 3;
          const int ao = (dy * 226 + dxx + c16) * 16 + c0;
          short8 a0 = *(const short8*)(sXH + hb0 + ao);   // B-frag, same addr
          short8 a1 = *(const short8*)(sXH + hb1 + ao);
#pragma unroll
          for (int n = 0; n < 2; ++n) {
            acc[0][n] = MFMA16(wf[kc][n], a0, acc[0][n]);
            acc[1][n] = MFMA16(wf[kc][n], a1, acc[1][n]);
          }
        }
        // D[ch][px]: lane=px(c16), regs=4 consecutive ch -> b64 writes
#pragma unroll
        for (int tt = 0; tt < 2; ++tt) {
          short* dst = sBUF + ((j & 1) * 2 + tt) * 2176 + c16 * 136;
#pragma unroll
          for (int n = 0; n < 2; ++n) {
            unsigned d0 = pk2bf(fmaxf(acc[tt][n][0] + bH[n][0], 0.f),
                                fmaxf(acc[tt][n][1] + bH[n][1], 0.f));
            unsigned d1 = pk2bf(fmaxf(acc[tt][n][2] + bH[n][2], 0.f),
                                fmaxf(acc[tt][n][3] + bH[n][3], 0.f));
            *(uint2v*)(dst + obase + 16 * n + 4 * q) = (uint2v){d0, d1};
          }
        }
      }
      sync_lds();
    }
  } else {
    // ====== G23 role, chan-quarter g: MLP2 (A=W2, B=h1) + (g<2) MLP3 =====
    const int g = wv - 4;
    const int obase = 32 * g;
    short8 w2f[4][2];                   // 32 VGPR; A-frag row obase+16n+c16
    short8 w3f[4];                      // 16 VGPR
#pragma unroll
    for (int kc = 0; kc < 4; ++kc)
#pragma unroll
      for (int n = 0; n < 2; ++n)
        w2f[kc][n] = *(const short8*)(w2g + (obase + 16 * n + c16) * 136 + kc * 32 + q8);
#pragma unroll
    for (int kc = 0; kc < 4; ++kc)
      w3f[kc] = *(const short8*)(w3g + c16 * 136 + kc * 32 + q8);
    float4v bG[2];
#pragma unroll
    for (int n = 0; n < 2; ++n)
      bG[n] = *(const float4v*)(b2p + obase + 16 * n + 4 * q);

    __syncthreads();                    // halo ready

    for (int j = 0; j < 16; ++j) {
      float4v acc3;
      int cb3 = 0, hglob3 = 0;
      const bool doG3 = (g < 2) && (j >= 2);
      if (doG3) {                       // residual (b128) -> MFMA C-in
        const int t3 = 2 * (j - 2) + g;
        cb3 = (t3 % 14) * 16; hglob3 = h0 + t3 / 14;
        const size_t pix = (size_t)(b * 224 + hglob3) * 224 + cb3 + c16;
        acc3 = *(const float4v*)(xs32 + pix * 16 + q * 4);
      }
      if (j >= 1 && j <= 14) {          // G2 quarter on tiles 2(j-1), 2(j-1)+1
        const short* srcA = sBUF + (((j - 1) & 1) * 2 + 0) * 2176;
        const short* srcB = sBUF + (((j - 1) & 1) * 2 + 1) * 2176;
        float4v acc2[2][2];
#pragma unroll
        for (int tt = 0; tt < 2; ++tt)
#pragma unroll
          for (int n = 0; n < 2; ++n) acc2[tt][n] = (float4v){0.f, 0.f, 0.f, 0.f};
#pragma unroll
        for (int kc = 0; kc < 4; ++kc) {
          short8 aA = *(const short8*)(srcA + c16 * 136 + kc * 32 + q8);  // B-frag
          short8 aB = *(const short8*)(srcB + c16 * 136 + kc * 32 + q8);
#pragma unroll
          for (int n = 0; n < 2; ++n) {
            acc2[0][n] = MFMA16(w2f[kc][n], aA, acc2[0][n]);
            acc2[1][n] = MFMA16(w2f[kc][n], aB, acc2[1][n]);
          }
        }
        // D[ch2][px] -> b64 writes, conflict-free
#pragma unroll
        for (int tt = 0; tt < 2; ++tt) {
          short* dsth2 = sH2 + ((j & 1) * 2 + tt) * 2176 + c16 * 136;
#pragma unroll
          for (int n = 0; n < 2; ++n) {
            unsigned d0 = pk2bf(fmaxf(acc2[tt][n][0] + bG[n][0], 0.f),
                                fmaxf(acc2[tt][n][1] + bG[n][1], 0.f));
            unsigned d1 = pk2bf(fmaxf(acc2[tt][n][2] + bG[n][2], 0.f),
                                fmaxf(acc2[tt][n][3] + bG[n][3], 0.f));
            *(uint2v*)(dsth2 + obase + 16 * n + 4 * q) = (uint2v){d0, d1};
          }
        }
      }
      if (doG3) {                       // G3 full-K + epilogue, tile 2(j-2)+g
        // A=w3f, B=h2frag: D[ch][px], lane=px(c16), regs=4 consecutive ch
        const short* srch2 = sH2 + (((j - 1) & 1) * 2 + g) * 2176;
#pragma unroll
        for (int kc = 0; kc < 4; ++kc) {
          short8 a = *(const short8*)(srch2 + c16 * 136 + kc * 32 + q8);
          acc3 = MFMA16(w3f[kc], a, acc3);
        }
        float4v vv;
#pragma unroll
        for (int r = 0; r < 4; ++r) vv[r] = fminf(fmaxf(acc3[r], 0.f), 1.f);
        if (LAST) {
#pragma unroll
          for (int r = 0; r < 4; ++r)
            dout[((size_t)(b * 16 + q * 4 + r) * 224 + hglob3) * 224 + cb3 + c16] = vv[r];
        } else {
          const size_t pix = (size_t)(b * 224 + hglob3) * 224 + cb3 + c16;
          *(float4v*)(xd32 + pix * 16 + q * 4) = vv;          // 1x b128
          *(uint2v*)(xd16 + pix * 16 + q * 4) =               // 1x b64
              (uint2v){pk2bf(vv[0], vv[1]), pk2bf(vv[2], vv[3])};
        }
      }
      sync_lds();
    }
  }
}

// ---------------------------------------------------------------------------
extern "C" void kernel_launch(void* const* d_in, const int* in_sizes, int n_in,
                              void* d_out, int out_size, void* d_ws, size_t ws_size,
                              hipStream_t stream) {
  const float* x  = (const float*)d_in[0];
  const float* wp = (const float*)d_in[1];
  const float* w1 = (const float*)d_in[2];
  const float* b1 = (const float*)d_in[3];
  const float* w2 = (const float*)d_in[4];
  const float* b2 = (const float*)d_in[5];
  const float* w3 = (const float*)d_in[6];

  char* ws = (char*)d_ws;
  short* wEg = (short*)(ws + WS_WE);
  short* w2g = (short*)(ws + WS_W2);
  short* w3g = (short*)(ws + WS_W3);
  float* b1p = (float*)(ws + WS_B1);
  float* b2p = (float*)(ws + WS_B2);
  float* X32[2] = {(float*)(ws + WS_X32A), (float*)(ws + WS_X32B)};
  short* X16[2] = {(short*)(ws + WS_X16A), (short*)(ws + WS_X16B)};

  prep_x<<<12544, 256, 0, stream>>>(x, X32[0], X16[0]);
  prep_w<<<163, 256, 0, stream>>>(wp, w1, b1, w2, b2, w3, wEg, w2g, w3g, b1p, b2p);

  for (int s = 0; s < 39; ++s) {
    int sb = s & 1;
    ca_step<false><<<448, 512, 0, stream>>>(wEg, w2g, w3g, b1p, b2p,
                                            X32[sb], X16[sb],
                                            X32[1 - sb], X16[1 - sb], nullptr);
  }
  ca_step<true><<<448, 512, 0, stream>>>(wEg, w2g, w3g, b1p, b2p,
                                         X32[1], X16[1],
                                         X32[0], X16[0], (float*)d_out);
}